// Round 11
// baseline (1180.467 us; speedup 1.0000x reference)
//
#include <hip/hip_runtime.h>

// ---------------- problem constants ----------------
#define LL 2048
#define BB 16
#define HH 512
#define PP 256
#define MM (LL*BB)   // 32768 rows
#define NN 512
#define KK 512
#define NC 64        // scan chunks
#define CLEN 32

typedef __bf16 bf16x8 __attribute__((ext_vector_type(8)));
typedef float  f32x4  __attribute__((ext_vector_type(4)));

__device__ __forceinline__ unsigned short f2bf(float f) {
  unsigned u = __builtin_bit_cast(unsigned, f);
  u = (u + 0x7fffu + ((u >> 16) & 1u)) >> 16;   // RNE
  return (unsigned short)u;
}
__device__ __forceinline__ float bf2f(unsigned short s) {
  unsigned u = ((unsigned)s) << 16;
  return __builtin_bit_cast(float, u);
}

// ---------------- dtype detection for `d` ----------------
__global__ void detect_kernel(const unsigned int* __restrict__ dw, int* __restrict__ flag) {
  __shared__ int sInt, sFloat;
  if (threadIdx.x == 0) { sInt = 1; sFloat = 1; }
  __syncthreads();
  int allInt = 1, allFloat = 1;
  for (int i = threadIdx.x; i < 8192; i += 256) {
    unsigned v = dw[i];
    if (v > 1u) allInt = 0;
    if (v != 0u && v != 0x3f800000u) allFloat = 0;
  }
  if (!allInt) atomicAnd(&sInt, 0);
  if (!allFloat) atomicAnd(&sFloat, 0);
  __syncthreads();
  if (threadIdx.x == 0) *flag = sInt ? 0 : (sFloat ? 1 : 2);
}

__device__ __forceinline__ float keep_val(const void* d, int flag, int idx) {
  if (flag == 0) return 1.f - (float)((const int*)d)[idx];
  if (flag == 1) return 1.f - ((const float*)d)[idx];
  return 1.f - (float)((const unsigned char*)d)[idx];
}

// ---------------- weight precompute ----------------
__global__ void precompute_kernel(
    const float* __restrict__ Lre, const float* __restrict__ Lim,
    const float* __restrict__ Bre, const float* __restrict__ Bim,
    const float* __restrict__ Cre, const float* __restrict__ Cim,
    const float* __restrict__ lstep, const float* __restrict__ w2,
    unsigned short* __restrict__ W1t, unsigned short* __restrict__ W2t,
    unsigned short* __restrict__ W3t, float* __restrict__ lam_re,
    float* __restrict__ lam_im) {
  int t = blockIdx.x * 256 + threadIdx.x;   // 0..262143
  int k = t & (KK - 1);
  int n = t >> 9;
  {
    int p = n & (PP - 1);
    float lr = Lre[p], li = Lim[p];
    float st = expf(lstep[p]);
    float er = expf(lr * st);
    float ang = li * st;
    float lbr = er * cosf(ang), lbi = er * sinf(ang);
    float den = lr * lr + li * li;
    float wr = ((lbr - 1.f) * lr + lbi * li) / den;
    float wi = (lbi * lr - (lbr - 1.f) * li) / den;
    float br = Bre[p * HH + k], bi = Bim[p * HH + k];
    float v = (n < PP) ? (wr * br - wi * bi) : (wr * bi + wi * br);
    W1t[(size_t)n * KK + k] = f2bf(v);
  }
  {
    float v = (k < PP) ? (2.f * Cre[n * PP + k]) : (-2.f * Cim[n * PP + (k - PP)]);
    W2t[(size_t)n * KK + k] = f2bf(v);
  }
  W3t[(size_t)n * KK + k] = f2bf(w2[(size_t)k * HH + n]);
  if (t < PP) {
    float lr = Lre[t], li = Lim[t];
    float st = expf(lstep[t]);
    float er = expf(lr * st);
    float ang = li * st;
    lam_re[t] = er * cosf(ang);
    lam_im[t] = er * sinf(ang);
  }
}

// ---------------- LayerNorm (1 wave per 512-wide row, 4 rows/block) -------------
__global__ void ln1_kernel(const float* __restrict__ x, const float* __restrict__ sc,
                           const float* __restrict__ bs, unsigned short* __restrict__ xn) {
  int row = blockIdx.x * 4 + (threadIdx.x >> 6);
  int lane = threadIdx.x & 63;
  const float4* xr = (const float4*)(x + (size_t)row * HH) + lane * 2;
  float4 a = xr[0], b = xr[1];
  float s = (a.x + a.y) + (a.z + a.w) + (b.x + b.y) + (b.z + b.w);
  float q = a.x * a.x + a.y * a.y + a.z * a.z + a.w * a.w +
            b.x * b.x + b.y * b.y + b.z * b.z + b.w * b.w;
#pragma unroll
  for (int off = 32; off; off >>= 1) { s += __shfl_xor(s, off); q += __shfl_xor(q, off); }
  float mean = s * (1.f / HH);
  float var = fmaxf(q * (1.f / HH) - mean * mean, 0.f);
  float rstd = rsqrtf(var + 1e-6f);
  const float4* scp = (const float4*)sc + lane * 2;
  const float4* bsp = (const float4*)bs + lane * 2;
  float4 s0 = scp[0], s1 = scp[1], b0 = bsp[0], b1 = bsp[1];
  unsigned short o[8];
  o[0] = f2bf((a.x - mean) * rstd * s0.x + b0.x);
  o[1] = f2bf((a.y - mean) * rstd * s0.y + b0.y);
  o[2] = f2bf((a.z - mean) * rstd * s0.z + b0.z);
  o[3] = f2bf((a.w - mean) * rstd * s0.w + b0.w);
  o[4] = f2bf((b.x - mean) * rstd * s1.x + b1.x);
  o[5] = f2bf((b.y - mean) * rstd * s1.y + b1.y);
  o[6] = f2bf((b.z - mean) * rstd * s1.z + b1.z);
  o[7] = f2bf((b.w - mean) * rstd * s1.w + b1.w);
  uint4 pk;
  pk.x = o[0] | ((unsigned)o[1] << 16);
  pk.y = o[2] | ((unsigned)o[3] << 16);
  pk.z = o[4] | ((unsigned)o[5] << 16);
  pk.w = o[6] | ((unsigned)o[7] << 16);
  *((uint4*)(xn + (size_t)row * HH) + lane) = pk;
}

// LN + GELU: reads ys (bf16), writes y (bf16) and x1 = gelu(y) (bf16)
__global__ void ln2_kernel(const unsigned short* __restrict__ ys, const float* __restrict__ sc,
                           const float* __restrict__ bs, unsigned short* __restrict__ y,
                           unsigned short* __restrict__ x1) {
  int row = blockIdx.x * 4 + (threadIdx.x >> 6);
  int lane = threadIdx.x & 63;
  uint4 pin = *((const uint4*)(ys + (size_t)row * HH) + lane);
  float v[8];
  v[0] = bf2f((unsigned short)(pin.x & 0xffff)); v[1] = bf2f((unsigned short)(pin.x >> 16));
  v[2] = bf2f((unsigned short)(pin.y & 0xffff)); v[3] = bf2f((unsigned short)(pin.y >> 16));
  v[4] = bf2f((unsigned short)(pin.z & 0xffff)); v[5] = bf2f((unsigned short)(pin.z >> 16));
  v[6] = bf2f((unsigned short)(pin.w & 0xffff)); v[7] = bf2f((unsigned short)(pin.w >> 16));
  float s = 0.f, q = 0.f;
#pragma unroll
  for (int j = 0; j < 8; j++) { s += v[j]; q += v[j] * v[j]; }
#pragma unroll
  for (int off = 32; off; off >>= 1) { s += __shfl_xor(s, off); q += __shfl_xor(q, off); }
  float mean = s * (1.f / HH);
  float var = fmaxf(q * (1.f / HH) - mean * mean, 0.f);
  float rstd = rsqrtf(var + 1e-6f);
  const float4* scp = (const float4*)sc + lane * 2;
  const float4* bsp = (const float4*)bs + lane * 2;
  float4 s0 = scp[0], s1 = scp[1], b0 = bsp[0], b1 = bsp[1];
  float scv[8] = { s0.x, s0.y, s0.z, s0.w, s1.x, s1.y, s1.z, s1.w };
  float bsv[8] = { b0.x, b0.y, b0.z, b0.w, b1.x, b1.y, b1.z, b1.w };
  unsigned short oy[8], og[8];
#pragma unroll
  for (int j = 0; j < 8; j++) {
    float yv = (v[j] - mean) * rstd * scv[j] + bsv[j];
    oy[j] = f2bf(yv);
    float g = 0.5f * yv * (1.f + tanhf(0.7978845608f * (yv + 0.044715f * yv * yv * yv)));
    og[j] = f2bf(g);
  }
  uint4 py, pg;
  py.x = oy[0] | ((unsigned)oy[1] << 16); py.y = oy[2] | ((unsigned)oy[3] << 16);
  py.z = oy[4] | ((unsigned)oy[5] << 16); py.w = oy[6] | ((unsigned)oy[7] << 16);
  pg.x = og[0] | ((unsigned)og[1] << 16); pg.y = og[2] | ((unsigned)og[3] << 16);
  pg.z = og[4] | ((unsigned)og[5] << 16); pg.w = og[6] | ((unsigned)og[7] << 16);
  *((uint4*)(y  + (size_t)row * HH) + lane) = py;
  *((uint4*)(x1 + (size_t)row * HH) + lane) = pg;
}

// ===== R8 gemmP (best measured: 42.0us) + 2-way-free swizzle ((row>>1)&3) =====
// BK=32, A 4-buf (dist 3) / B 3-buf (dist 2), 512 thr = 8 waves (2x4), counted vmcnt(3).
template <int EPI>
__global__ __launch_bounds__(512, 4) void gemmP_kernel(
    const unsigned short* __restrict__ A, const unsigned short* __restrict__ Wt,
    void* __restrict__ Cout, const float* __restrict__ Dvec,
    const unsigned short* __restrict__ aux16, const float* __restrict__ skip) {
  __shared__ char lds[57344];            // A: 4x8KB @0; B: 3x8KB @32KB; epilogue reuse
  unsigned short* lA = (unsigned short*)lds;
  unsigned short* lB = (unsigned short*)(lds + 32768);
  const int tid = threadIdx.x;
  const int w = tid >> 6, lane = tid & 63;
  const int wr = w >> 2, wc = w & 3;
  const int l15 = lane & 15, g16 = lane >> 4;
  const int wgid = blockIdx.x;
  const int xcd = wgid & 7, bidx = wgid >> 3;    // 1024 blocks; n-quads share an XCD
  const int m0 = (xcd * 32 + (bidx >> 2)) * 128;
  const int n0 = (bidx & 3) * 128;

  // staging: slot t (row=t>>2, ch=t&3); slot holds global chunk ch ^ ((row>>1)&3)
  const int sRow = tid >> 2;
  const int sC = (tid & 3) ^ ((sRow >> 1) & 3);
  const unsigned short* aSrc = A + (size_t)(m0 + sRow) * KK + sC * 8;
  const unsigned short* bSrc = Wt + (size_t)(n0 + sRow) * KK + sC * 8;

  auto sA = [&](int buf, int kt) {
    __builtin_amdgcn_global_load_lds(
        (const __attribute__((address_space(1))) void*)(aSrc + kt * 32),
        (__attribute__((address_space(3))) void*)(lA + buf * 4096 + (w * 64) * 8), 16, 0, 0);
  };
  auto sB = [&](int buf, int kt) {
    __builtin_amdgcn_global_load_lds(
        (const __attribute__((address_space(1))) void*)(bSrc + kt * 32),
        (__attribute__((address_space(3))) void*)(lB + buf * 4096 + (w * 64) * 8), 16, 0, 0);
  };
  auto rdA = [&](int buf, int fm) -> bf16x8 {
    int row = wr * 64 + fm * 16 + l15;
    return *(const bf16x8*)(lA + buf * 4096 + row * 32 + (g16 ^ ((row >> 1) & 3)) * 8);
  };
  auto rdB = [&](int buf, int fn) -> bf16x8 {
    int row = wc * 32 + fn * 16 + l15;
    return *(const bf16x8*)(lB + buf * 4096 + row * 32 + (g16 ^ ((row >> 1) & 3)) * 8);
  };

  f32x4 acc[4][2];
#pragma unroll
  for (int i = 0; i < 4; i++)
#pragma unroll
    for (int j = 0; j < 2; j++) acc[i][j] = (f32x4){0.f, 0.f, 0.f, 0.f};

  // prologue queue (oldest->newest): B0 A0 B1 A1 A2 ; need B0,A0 -> 3 in flight
  sB(0, 0); sA(0, 0); sB(1, 1); sA(1, 1); sA(2, 2);
  asm volatile("s_waitcnt vmcnt(3)" ::: "memory");
  __builtin_amdgcn_s_barrier();

#pragma unroll
  for (int k = 0; k < 16; ++k) {
    bf16x8 aF[4], bF[2];
#pragma unroll
    for (int fm = 0; fm < 4; fm++) aF[fm] = rdA(k & 3, fm);
#pragma unroll
    for (int fn = 0; fn < 2; fn++) bF[fn] = rdB(k % 3, fn);
    if (k + 2 < 16) sB((k + 2) % 3, k + 2);
    if (k + 3 < 16) sA((k + 3) & 3, k + 3);
    asm volatile("s_waitcnt lgkmcnt(0)" ::: "memory");
    __builtin_amdgcn_sched_barrier(0);
    __builtin_amdgcn_s_setprio(1);
#pragma unroll
    for (int fm = 0; fm < 4; fm++)
#pragma unroll
      for (int fn = 0; fn < 2; fn++)
        acc[fm][fn] = __builtin_amdgcn_mfma_f32_16x16x32_bf16(aF[fm], bF[fn], acc[fm][fn], 0, 0, 0);
    __builtin_amdgcn_s_setprio(0);
    if (k <= 12)      asm volatile("s_waitcnt vmcnt(3)" ::: "memory");
    else if (k == 13) asm volatile("s_waitcnt vmcnt(2)" ::: "memory");
    else              asm volatile("s_waitcnt vmcnt(0)" ::: "memory");
    __builtin_amdgcn_s_barrier();
  }

  // ---- bounce epilogue: 8 chunks of 16 rows; coalesced streams ----
  if (EPI == 0 || EPI == 1) {
    unsigned short* lbf = (unsigned short*)lds;   // [16][136] bf16
#pragma unroll
    for (int ch = 0; ch < 8; ++ch) {
      if (wr == (ch >> 2)) {
        int fm = ch & 3;
#pragma unroll
        for (int fn = 0; fn < 2; fn++) {
          int col = wc * 32 + fn * 16 + l15;
#pragma unroll
          for (int jj = 0; jj < 4; jj++)
            lbf[(g16 * 4 + jj) * 136 + col] = f2bf(acc[fm][fn][jj]);
        }
      }
      __syncthreads();
      {
        int r = tid >> 5, tc = tid & 31;
        int grow = m0 + ch * 16 + r;
        int gcol = n0 + tc * 4;
        ushort4 v = *(const ushort4*)&lbf[r * 136 + tc * 4];
        if (EPI == 0) {
          *(ushort4*)(((unsigned short*)Cout) + (size_t)grow * NN + gcol) = v;
        } else {
          ushort4 au = *(const ushort4*)(aux16 + (size_t)grow * NN + gcol);
          float4 d = *(const float4*)&Dvec[gcol];
          ushort4 o;
          o.x = f2bf(bf2f(v.x) + d.x * bf2f(au.x));
          o.y = f2bf(bf2f(v.y) + d.y * bf2f(au.y));
          o.z = f2bf(bf2f(v.z) + d.z * bf2f(au.z));
          o.w = f2bf(bf2f(v.w) + d.w * bf2f(au.w));
          *(ushort4*)(((unsigned short*)Cout) + (size_t)grow * NN + gcol) = o;
        }
      }
      __syncthreads();
    }
  } else {
    float* lf = (float*)lds;                       // [16][132] f32
#pragma unroll
    for (int ch = 0; ch < 8; ++ch) {
      if (wr == (ch >> 2)) {
        int fm = ch & 3;
#pragma unroll
        for (int fn = 0; fn < 2; fn++) {
          int col = wc * 32 + fn * 16 + l15;
#pragma unroll
          for (int jj = 0; jj < 4; jj++)
            lf[(g16 * 4 + jj) * 132 + col] = acc[fm][fn][jj];
        }
      }
      __syncthreads();
      {
        int r = tid >> 5, tc = tid & 31;
        int grow = m0 + ch * 16 + r;
        int gcol = n0 + tc * 4;
        float4 v = *(const float4*)&lf[r * 132 + tc * 4];
        float4 d = *(const float4*)&Dvec[gcol];
        float4 sk = *(const float4*)(skip + (size_t)grow * NN + gcol);
        ushort4 au = *(const ushort4*)(aux16 + (size_t)grow * NN + gcol);
        float4 o;
        o.x = sk.x + bf2f(au.x) / (1.f + expf(-(v.x + d.x)));
        o.y = sk.y + bf2f(au.y) / (1.f + expf(-(v.y + d.y)));
        o.z = sk.z + bf2f(au.z) / (1.f + expf(-(v.z + d.z)));
        o.w = sk.w + bf2f(au.w) / (1.f + expf(-(v.w + d.w)));
        *(float4*)(((float*)Cout) + (size_t)grow * NN + gcol) = o;
      }
      __syncthreads();
    }
  }
}

// ===== fused scan: decoupled-lookback, one kernel, Bu read once (LDS-cached) =====
// 1024 blocks = (c 0..63) x (b 0..15) = exactly 4/CU x 256 CU -> all co-resident
// (launch_bounds(256,4) caps VGPR<=128; 32KB LDS -> 4+/CU). Per block:
//   1) stage Bu chunk (32 rows x 512 bf16 = 32KB) to LDS — row j = 64 x 16B chunks;
//      slot = sw*256+tid; j = slot>>6, col8 = slot&63; linear LDS dest slot*8
//      == j*512 + col8*8 matches [j][512] read layout (rule #21).
//   2) local summary (A,s); publish agg + release flag
//   3) lookback cc=0..c-1 (batched 8: acquire-poll flags, pipelined agg loads, combine)
//   4) replay from LDS with carry; write xs; block c=63 writes new_hidden
__global__ __launch_bounds__(256, 4) void scanF_kernel(
    const unsigned short* __restrict__ Bu, const void* __restrict__ d,
    const int* __restrict__ dflag, const float* __restrict__ lam_re,
    const float* __restrict__ lam_im, const float* __restrict__ hr0,
    const float* __restrict__ hi0, float4* __restrict__ agg,
    int* __restrict__ flags, unsigned short* __restrict__ xs,
    float* __restrict__ outHid) {
  __shared__ unsigned short lbu[32 * 512];   // 32KB
  const int tid = threadIdx.x;
  const int wg = blockIdx.x;
  const int c = wg >> 4, b = wg & 15;
  const int l0 = c * CLEN;
  // stage Bu chunk: 8 sweeps x 256 threads; each wave covers one full 1KB row
#pragma unroll
  for (int sw = 0; sw < 8; sw++) {
    int slot = sw * 256 + tid;               // 0..2047
    int j = slot >> 6, col8 = slot & 63;     // 64 x 16B chunks per 512-elem row
    const unsigned short* g = Bu + ((size_t)(l0 + j) * BB + b) * NN + col8 * 8;
    unsigned short* dp = lbu + (sw * 256 + (tid & ~63)) * 8;   // wave-uniform base
    __builtin_amdgcn_global_load_lds((const __attribute__((address_space(1))) void*)g,
                                     (__attribute__((address_space(3))) void*)dp, 16, 0, 0);
  }
  const int fl = *dflag;
  const int p = tid;
  const float lr = lam_re[p], li = lam_im[p];
  asm volatile("s_waitcnt vmcnt(0)" ::: "memory");
  __syncthreads();
  // phase 1: local summary from zero state
  float Ar = 1.f, Ai = 0.f, sr = 0.f, si = 0.f;
  for (int j = 0; j < CLEN; j++) {
    float kp = keep_val(d, fl, (l0 + j) * BB + b);
    float ar = lr * kp, ai = li * kp;
    float bur = bf2f(lbu[j * 512 + p]), bui = bf2f(lbu[j * 512 + 256 + p]);
    float nsr = ar * sr - ai * si + bur;
    float nsi = ar * si + ai * sr + bui;
    sr = nsr; si = nsi;
    float nar = ar * Ar - ai * Ai;
    float nai = ar * Ai + ai * Ar;
    Ar = nar; Ai = nai;
  }
  agg[((c * BB + b) << 8) + p] = make_float4(Ar, Ai, sr, si);
  __threadfence();
  __syncthreads();
  if (tid == 0)
    __hip_atomic_store(&flags[c * BB + b], 1, __ATOMIC_RELEASE, __HIP_MEMORY_SCOPE_AGENT);
  // lookback: carry = chunks 0..c-1 applied (in order) to h0
  float cr = hr0[b * PP + p], ci = hi0[b * PP + p];
  for (int cc = 0; cc < c; cc += 8) {
    int bs = c - cc; bs = bs > 8 ? 8 : bs;
#pragma unroll
    for (int i = 0; i < 8; i++)
      if (i < bs)
        while (__hip_atomic_load(&flags[(cc + i) * BB + b], __ATOMIC_ACQUIRE,
                                 __HIP_MEMORY_SCOPE_AGENT) == 0)
          __builtin_amdgcn_s_sleep(1);
    float4 av[8];
#pragma unroll
    for (int i = 0; i < 8; i++)
      if (i < bs) av[i] = agg[(((cc + i) * BB + b) << 8) + p];
#pragma unroll
    for (int i = 0; i < 8; i++)
      if (i < bs) {
        float ncr = av[i].x * cr - av[i].y * ci + av[i].z;
        float nci = av[i].x * ci + av[i].y * cr + av[i].w;
        cr = ncr; ci = nci;
      }
  }
  if (c == NC - 1) {   // final hidden = own chunk applied to carry
    float fr = Ar * cr - Ai * ci + sr;
    float fi = Ar * ci + Ai * cr + si;
    outHid[b * PP + p] = fr;
    outHid[BB * PP + b * PP + p] = fi;
  }
  // phase 2: replay with carry (Bu from LDS), write xs
  float hr = cr, hi = ci;
  for (int j = 0; j < CLEN; j++) {
    float kp = keep_val(d, fl, (l0 + j) * BB + b);
    float ar = lr * kp, ai = li * kp;
    float bur = bf2f(lbu[j * 512 + p]), bui = bf2f(lbu[j * 512 + 256 + p]);
    float nhr = ar * hr - ai * hi + bur;
    float nhi = ar * hi + ai * hr + bui;
    hr = nhr; hi = nhi;
    size_t ro = ((size_t)(l0 + j) * BB + b) * NN;
    xs[ro + p] = f2bf(hr);
    xs[ro + PP + p] = f2bf(hi);
  }
}

// ---------------- launcher ----------------
extern "C" void kernel_launch(void* const* d_in, const int* in_sizes, int n_in,
                              void* d_out, int out_size, void* d_ws, size_t ws_size,
                              hipStream_t stream) {
  const float* x    = (const float*)d_in[0];
  const void*  dmask= d_in[1];
  const float* hidr = (const float*)d_in[2];
  const float* hidi = (const float*)d_in[3];
  const float* Lre  = (const float*)d_in[4];
  const float* Lim  = (const float*)d_in[5];
  const float* Bre  = (const float*)d_in[6];
  const float* Bim  = (const float*)d_in[7];
  const float* Cre  = (const float*)d_in[8];
  const float* Cim  = (const float*)d_in[9];
  const float* Dv   = (const float*)d_in[10];
  const float* lst  = (const float*)d_in[11];
  const float* lsc  = (const float*)d_in[12];
  const float* lbs  = (const float*)d_in[13];
  const float* w2   = (const float*)d_in[14];
  const float* b2   = (const float*)d_in[15];
  float* out = (float*)d_out;

  char* ws = (char*)d_ws;
  size_t off = 0;
  auto alloc = [&](size_t bytes) -> void* {
    void* p = ws + off;
    off += (bytes + 255) & ~(size_t)255;
    return p;
  };
  unsigned short* xn  = (unsigned short*)alloc((size_t)MM * KK * 2);  // 32MB; reused as y
  unsigned short* xs  = (unsigned short*)alloc((size_t)MM * KK * 2);  // 32MB; reused as x1
  unsigned short* Bu  = (unsigned short*)alloc((size_t)MM * NN * 2);  // 32MB bf16; reused as ys
  unsigned short* W1t = (unsigned short*)alloc((size_t)NN * KK * 2);
  unsigned short* W2t = (unsigned short*)alloc((size_t)NN * KK * 2);
  unsigned short* W3t = (unsigned short*)alloc((size_t)NN * KK * 2);
  float* lam_re = (float*)alloc(PP * 4);
  float* lam_im = (float*)alloc(PP * 4);
  float4* agg   = (float4*)alloc((size_t)NC * BB * PP * 16);   // 4MB
  int* flags    = (int*)alloc(NC * BB * 4);
  int* dflag    = (int*)alloc(256);
  unsigned short* y   = xn;   // reuse after GEMM2 consumed xn
  unsigned short* x1  = xs;   // reuse after GEMM2 consumed xs
  unsigned short* ysb = Bu;   // reuse after scan consumed Bu

  hipMemsetAsync(flags, 0, NC * BB * 4, stream);   // lookback flags must start 0 each call
  detect_kernel<<<1, 256, 0, stream>>>((const unsigned int*)dmask, dflag);
  precompute_kernel<<<1024, 256, 0, stream>>>(Lre, Lim, Bre, Bim, Cre, Cim, lst, w2,
                                              W1t, W2t, W3t, lam_re, lam_im);
  ln1_kernel<<<MM / 4, 256, 0, stream>>>(x, lsc, lbs, xn);
  gemmP_kernel<0><<<1024, 512, 0, stream>>>(xn, W1t, Bu, nullptr, nullptr, nullptr);
  scanF_kernel<<<NC * BB, 256, 0, stream>>>(Bu, dmask, dflag, lam_re, lam_im,
                                            hidr, hidi, agg, flags, xs, out);
  gemmP_kernel<1><<<1024, 512, 0, stream>>>(xs, W2t, ysb, Dv, xn, nullptr);
  ln2_kernel<<<MM / 4, 256, 0, stream>>>(ysb, lsc, lbs, y, x1);
  gemmP_kernel<2><<<1024, 512, 0, stream>>>(x1, W3t, out + 2 * BB * PP, b2, y, x);
}